// Round 1
// 90.210 us; speedup vs baseline: 1.0029x; 1.0029x over previous
//
#include <hip/hip_runtime.h>

// KAN conv as densified GEMM: out[px,f] = sum_k Basis[px,k] * W[k,f]
//   px = (b,p,q) 8192, f = 64, K = 16 chunks x 640:
//   chunk kl in [0,576): spline (cl*144 + ij*16 + g), taps (1-fr)@idx, fr@idx+1
//   chunk kl in [576,640): silu at cl*16 + ij (ij<9), rest zero-pad (W rows 0)
// W pre-swizzled to MFMA 16x16x32 f16 B-fragment order. Basis built in LDS with
// self-clearing scatter. This revision:
//   * scatter vectorized: one v4f x-load covers the 4 channels of a (px,ij)
//     event (288 events instead of 1152 scalar ones)
//   * x-prefetch issued AFTER the first barrier so the compiler's
//     vmcnt(0)-before-s_barrier drain lands at barrier 2, hidden under MFMA
//   * MFMA inner loop explicitly 2-deep pipelined (load s+1 while computing s)
//   * prep_wsw vectorized 8x (2 v4f cp loads + 1 w1 scalar -> 1 v8h store)
// 3-way K-split -> partials + combine kernel. No atomics, no memset.

typedef _Float16 v8h __attribute__((ext_vector_type(8)));
typedef float    v4f __attribute__((ext_vector_type(4)));

#define NSLOT   655360            // 10240 * 64 f16
#define PARTOFF 1310720           // bytes: wsw size
#define NPART   524288            // floats per partial (8192*64)

// Wsw slot ((ks*4+nt)*64+lane)*8+j = W[k=ks*32+(lane>>4)*8+j][f=nt*16+(lane&15)]
// One thread per slot-group of 8 (j=0..7): k-block is 8-aligned, never crosses a
// chunk (640%8==0), spline/silu boundary (576%8==0), c (144%8==0) or ij (aligned
// 8-blocks stay within one 16-slot g-range), so the whole group shares one
// (chunk,c,ij) and reads 8 consecutive cp floats.
__global__ __launch_bounds__(256) void prep_wsw(const float* __restrict__ cp,
                                                const float* __restrict__ w1,
                                                const float* __restrict__ w2,
                                                _Float16* __restrict__ wsw) {
    int tid  = blockIdx.x * 256 + threadIdx.x;   // 0..81919
    int lane = tid & 63;
    int rest = tid >> 6;
    int nt   = rest & 3;
    int ks   = rest >> 2;
    int kb   = ks * 32 + ((lane >> 4) << 3);     // 8-aligned k base
    int f    = (nt << 4) + (lane & 15);
    int chunk = kb / 640;
    int klb   = kb - chunk * 640;
    v8h out;
    if (klb < 576) {
        int c  = (chunk << 2) + klb / 144;
        int rb = klb % 144;                      // 8-aligned, ij constant
        int ij = rb >> 4;
        float w = w1[f * 576 + c * 9 + ij];
        const v4f* cpp = (const v4f*)(cp + (size_t)f * 9216 + c * 144 + rb);
        v4f lo = cpp[0], hi = cpp[1];
#pragma unroll
        for (int j = 0; j < 4; ++j) {
            out[j]     = (_Float16)(w * lo[j]);
            out[j + 4] = (_Float16)(w * hi[j]);
        }
    } else {
        int i2 = klb - 576;                      // 8-aligned
        int c  = (chunk << 2) + (i2 >> 4);
        if ((i2 & 15) == 0) {                    // ij = 0..7, all valid
#pragma unroll
            for (int j = 0; j < 8; ++j)
                out[j] = (_Float16)w2[f * 576 + c * 9 + j];
        } else {                                 // ij = 8..15, only ij==8 valid
#pragma unroll
            for (int j = 0; j < 8; ++j) out[j] = (_Float16)0.f;
            out[0] = (_Float16)w2[f * 576 + c * 9 + 8];
        }
    }
    ((v8h*)wsw)[tid] = out;
}

// grid 768: kh = blk>>8 (chunk range {0-5,6-10,11-15}), rowid = blk&255 = (b,p).
// WG = 32 px (one image row). 4 waves split each chunk's 20 ksteps (5 each);
// each wave holds the full 32x64 fp32 accumulator; LDS reduce at the end.
__global__ __launch_bounds__(256, 3) void kan_mfma(const float* __restrict__ x,
                                                   const _Float16* __restrict__ wsw,
                                                   float* __restrict__ part) {
    __shared__ __align__(16) char smem[41472];
    _Float16* sb  = (_Float16*)smem;       // [32][648] f16 basis (stride 648)
    float*    red = (float*)smem;          // [4][32][65] f32 reduce, aliases sb

    int blk   = blockIdx.x;
    int kh    = blk >> 8;
    int rowid = blk & 255;
    int b = rowid >> 5, p = rowid & 31;
    int t = threadIdx.x, wv = t >> 6, lane = t & 63;
    int m = lane & 15, kq = lane >> 4;

    const int chs[4] = {0, 6, 11, 16};
    int ch0 = chs[kh], ch1 = chs[kh + 1];

    const float* xb = x + (size_t)b * 65536;

    // ---- per-thread event geometry: 288 (px,ij) items, <=2 per thread ----
    int xoff[2], sbb[2], silb[2];
    unsigned prevPack[2] = {0u, 0u};
#pragma unroll
    for (int it = 0; it < 2; ++it) {
        int e  = t + it * 256;
        int ec = e < 288 ? e : 0;            // dummy for inactive slots
        int px = ec / 9;
        int ij = ec - px * 9;
        int di = ij / 3;
        int dj = ij - di * 3;
        int row = p + di - 1;
        int col = px + dj - 1;
        bool ok  = ((unsigned)row < 32u) && ((unsigned)col < 32u);
        xoff[it] = ok ? ((row * 32 + col) * 64) : -1;   // sign = halo flag
        sbb[it]  = px * 648 + ij * 16;
        silb[it] = px * 648 + 576 + ij;
    }

    v4f z4 = (v4f){0.f, 0.f, 0.f, 0.f};

    // prologue prefetch for first chunk (issued before the zero-fill so the
    // ds_writes cover part of the load latency)
    v4f vbuf[2];
#pragma unroll
    for (int it = 0; it < 2; ++it)
        vbuf[it] = (xoff[it] >= 0) ? *(const v4f*)(xb + xoff[it] + ch0 * 4) : z4;

    // one-time zero of the whole basis region
    for (int i4 = t; i4 < 2592; i4 += 256) ((v4f*)sb)[i4] = z4;

    v4f acc[2][4];
#pragma unroll
    for (int i = 0; i < 2; ++i)
#pragma unroll
        for (int n = 0; n < 4; ++n) acc[i][n] = z4;

    __syncthreads();   // basis zeroed, prologue loads drained here (one-time)

    for (int gch = ch0; gch < ch1; ++gch) {
        // ---- scatter: 4 channels per item from one prefetched v4f ----
#pragma unroll
        for (int it = 0; it < 2; ++it) {
            if (t + it * 256 < 288) {
                v4f xv = vbuf[it];
                unsigned pp = prevPack[it];
                unsigned np = 0;
                _Float16* rp = sb + sbb[it];
                _Float16* sp = sb + silb[it];
#pragma unroll
                for (int cl = 0; cl < 4; ++cl) {
                    float v  = xv[cl];
                    float xc = fminf(fmaxf(v, -1.f), 1.f);
                    float tt = (xc + 1.f) * 7.5f;
                    int idx  = (int)tt;
                    if (idx > 14) idx = 14;
                    float fr = tt - (float)idx;
                    float sv = v * __builtin_amdgcn_rcpf(1.f + __expf(-v));
                    _Float16* q = rp + cl * 144;
                    if (gch > ch0) {             // self-clear previous entries
                        int pi = (pp >> (cl * 8)) & 255;
                        q[pi]     = (_Float16)0.f;
                        q[pi + 1] = (_Float16)0.f;
                    }
                    q[idx]     = (_Float16)(1.f - fr);
                    q[idx + 1] = (_Float16)fr;
                    sp[cl * 16] = (_Float16)sv;
                    np |= (unsigned)idx << (cl * 8);
                }
                prevPack[it] = np;
            }
        }
        __syncthreads();
        // ---- prefetch next chunk's x AFTER the barrier: the compiler's
        // vmcnt(0) drain now happens at the NEXT barrier, under the MFMA phase
        if (gch + 1 < ch1) {
#pragma unroll
            for (int it = 0; it < 2; ++it)
                vbuf[it] = (xoff[it] >= 0)
                         ? *(const v4f*)(xb + xoff[it] + (gch + 1) * 4) : z4;
        }
        // ---- MFMA: 20 ksteps, this wave takes 5; 2-deep pipelined ----
        const _Float16* ap = sb + m * 648 + (wv * 5) * 32 + kq * 8;
        const v8h* bp = (const v8h*)wsw + ((size_t)gch * 20 + wv * 5) * 256 + lane;
        v8h a0c = *(const v8h*)ap;
        v8h a1c = *(const v8h*)(ap + 16 * 648);
        v8h b0c = bp[0], b1c = bp[64], b2c = bp[128], b3c = bp[192];
#pragma unroll
        for (int s = 0; s < 5; ++s) {
            v8h a0n, a1n, b0n, b1n, b2n, b3n;
            if (s < 4) {
                const _Float16* ap2 = ap + (s + 1) * 32;
                a0n = *(const v8h*)ap2;
                a1n = *(const v8h*)(ap2 + 16 * 648);
                const v8h* bp2 = bp + (s + 1) * 256;
                b0n = bp2[0];
                b1n = bp2[64];
                b2n = bp2[128];
                b3n = bp2[192];
            }
            acc[0][0] = __builtin_amdgcn_mfma_f32_16x16x32_f16(a0c, b0c, acc[0][0], 0, 0, 0);
            acc[0][1] = __builtin_amdgcn_mfma_f32_16x16x32_f16(a0c, b1c, acc[0][1], 0, 0, 0);
            acc[0][2] = __builtin_amdgcn_mfma_f32_16x16x32_f16(a0c, b2c, acc[0][2], 0, 0, 0);
            acc[0][3] = __builtin_amdgcn_mfma_f32_16x16x32_f16(a0c, b3c, acc[0][3], 0, 0, 0);
            acc[1][0] = __builtin_amdgcn_mfma_f32_16x16x32_f16(a1c, b0c, acc[1][0], 0, 0, 0);
            acc[1][1] = __builtin_amdgcn_mfma_f32_16x16x32_f16(a1c, b1c, acc[1][1], 0, 0, 0);
            acc[1][2] = __builtin_amdgcn_mfma_f32_16x16x32_f16(a1c, b2c, acc[1][2], 0, 0, 0);
            acc[1][3] = __builtin_amdgcn_mfma_f32_16x16x32_f16(a1c, b3c, acc[1][3], 0, 0, 0);
            if (s < 4) {
                a0c = a0n; a1c = a1n;
                b0c = b0n; b1c = b1n; b2c = b2n; b3c = b3n;
            }
        }
        __syncthreads();
    }

    // ---- 4-wave LDS reduction, then plain coalesced stores to partial ----
#pragma unroll
    for (int mt = 0; mt < 2; ++mt)
#pragma unroll
        for (int nt = 0; nt < 4; ++nt)
#pragma unroll
            for (int r = 0; r < 4; ++r)
                red[wv * 2080 + (mt * 16 + kq * 4 + r) * 65 + nt * 16 + m] = acc[mt][nt][r];
    __syncthreads();
    int f = t & 63, pxg = t >> 6;
    float* op = part + (size_t)kh * NPART + rowid * 2048 + f;
#pragma unroll
    for (int i = 0; i < 8; ++i) {
        int px = pxg * 8 + i;
        float s = red[px * 65 + f] + red[2080 + px * 65 + f]
                + red[4160 + px * 65 + f] + red[6240 + px * 65 + f];
        op[px * 64] = s;
    }
}

__global__ __launch_bounds__(256) void combine(const float* __restrict__ part,
                                               float* __restrict__ out) {
    int i = blockIdx.x * 256 + threadIdx.x;
    v4f a = ((const v4f*)part)[i];
    v4f b = ((const v4f*)(part + NPART))[i];
    v4f c = ((const v4f*)(part + 2 * NPART))[i];
    ((v4f*)out)[i] = a + b + c;
}

extern "C" void kernel_launch(void* const* d_in, const int* in_sizes, int n_in,
                              void* d_out, int out_size, void* d_ws, size_t ws_size,
                              hipStream_t stream) {
    const float* x  = (const float*)d_in[0];
    const float* cp = (const float*)d_in[1];
    const float* w1 = (const float*)d_in[2];
    const float* w2 = (const float*)d_in[3];
    _Float16* wsw = (_Float16*)d_ws;                       // 1.31 MB
    float*    prt = (float*)((char*)d_ws + PARTOFF);       // 3 x 2 MB partials

    prep_wsw<<<320, 256, 0, stream>>>(cp, w1, w2, wsw);
    kan_mfma<<<768, 256, 0, stream>>>(x, wsw, prt);
    combine<<<512, 256, 0, stream>>>(prt, (float*)d_out);
}

// Round 3
// 87.838 us; speedup vs baseline: 1.0300x; 1.0270x over previous
//
#include <hip/hip_runtime.h>

// KAN conv as densified GEMM: out[px,f] = sum_k Basis[px,k] * W[k,f]
//   px = (b,p,q) 8192, f = 64, K = 16 chunks x 640:
//   chunk kl in [0,576): spline (cl*144 + ij*16 + g), taps (1-fr)@idx, fr@idx+1
//   chunk kl in [576,640): silu at cl*16 + ij (ij<9), rest zero-pad (W rows 0)
// W pre-swizzled to MFMA 16x16x32 f16 B-fragment order. Basis built in LDS with
// self-clearing scatter. THIS REVISION: 2 dispatches (was 3).
//   prep_wsw: build wsw (vectorized 8x) AND zero out[8192*64]
//   kan_mfma: 768 blocks (3-way K-split), epilogue atomicAdds straight into
//             out -- no partial buffers, no combine kernel. atomicAdd is
//             device-scope (cross-XCD safe); prep's zeros are visible via the
//             kernel-boundary release/acquire on the same stream.
// (Cooperative single-kernel fusion was tried and rejected: the cooperative
// launch validator refuses 768 blocks under its conservative occupancy model.)

typedef _Float16 v8h __attribute__((ext_vector_type(8)));
typedef float    v4f __attribute__((ext_vector_type(4)));

#define NSLOT8  81920             // v8h slot-groups in wsw (655360 f16 / 8)
#define NOUT4   131072            // v4f groups in out (8192*64 f32 / 4)

// Wsw slot ((ks*4+nt)*64+lane)*8+j = W[k=ks*32+(lane>>4)*8+j][f=nt*16+(lane&15)]
// One thread per slot-group of 8 (j=0..7): 8-aligned k never crosses a chunk
// (640%8==0), spline/silu boundary (576%8==0), c (144%8==0) or ij boundaries,
// so the whole group shares one (chunk,c,ij) and reads 8 consecutive cp floats.
__global__ __launch_bounds__(256) void prep_wsw(const float* __restrict__ cp,
                                                const float* __restrict__ w1,
                                                const float* __restrict__ w2,
                                                _Float16* __restrict__ wsw,
                                                float* __restrict__ out) {
    int tid = blockIdx.x * 256 + threadIdx.x;    // 0..131071 (512 blocks)
    if (tid < NSLOT8) {
        int lane = tid & 63;
        int rest = tid >> 6;
        int nt   = rest & 3;
        int ks   = rest >> 2;
        int kb   = ks * 32 + ((lane >> 4) << 3); // 8-aligned k base
        int f    = (nt << 4) + (lane & 15);
        int chunk = kb / 640;
        int klb   = kb - chunk * 640;
        v8h o;
        if (klb < 576) {
            int c  = (chunk << 2) + klb / 144;
            int rb = klb % 144;                  // 8-aligned, ij constant
            int ij = rb >> 4;
            float w = w1[f * 576 + c * 9 + ij];
            const v4f* cpp = (const v4f*)(cp + (size_t)f * 9216 + c * 144 + rb);
            v4f lo = cpp[0], hi = cpp[1];
#pragma unroll
            for (int j = 0; j < 4; ++j) {
            o[j]     = (_Float16)(w * lo[j]);
            o[j + 4] = (_Float16)(w * hi[j]);
            }
        } else {
            int i2 = klb - 576;                  // 8-aligned
            int c  = (chunk << 2) + (i2 >> 4);
            if ((i2 & 15) == 0) {                // ij = 0..7, all valid
#pragma unroll
                for (int j = 0; j < 8; ++j)
                    o[j] = (_Float16)w2[f * 576 + c * 9 + j];
            } else {                             // ij = 8..15, only ij==8 valid
#pragma unroll
                for (int j = 0; j < 8; ++j) o[j] = (_Float16)0.f;
                o[0] = (_Float16)w2[f * 576 + c * 9 + 8];
            }
        }
        ((v8h*)wsw)[tid] = o;
    }
    // zero the output accumulator (kan_mfma atomicAdds into it)
    if (tid < NOUT4) ((v4f*)out)[tid] = (v4f){0.f, 0.f, 0.f, 0.f};
}

// grid 768: kh = blk>>8 (chunk range {0-5,6-10,11-15}), rowid = blk&255 = (b,p).
// WG = 32 px (one image row). 4 waves split each chunk's 20 ksteps (5 each);
// each wave holds the full 32x64 fp32 accumulator; LDS reduce at the end, then
// atomicAdd into out (3 contenders/address, coalesced 64-lane bursts).
__global__ __launch_bounds__(256, 3) void kan_mfma(const float* __restrict__ x,
                                                   const _Float16* __restrict__ wsw,
                                                   float* __restrict__ out) {
    __shared__ __align__(16) char smem[41472];
    _Float16* sb  = (_Float16*)smem;       // [32][648] f16 basis (stride 648)
    float*    red = (float*)smem;          // [4][32][65] f32 reduce, aliases sb

    int blk   = blockIdx.x;
    int kh    = blk >> 8;
    int rowid = blk & 255;
    int b = rowid >> 5, p = rowid & 31;
    int t = threadIdx.x, wv = t >> 6, lane = t & 63;
    int m = lane & 15, kq = lane >> 4;

    const int chs[4] = {0, 6, 11, 16};
    int ch0 = chs[kh], ch1 = chs[kh + 1];

    const float* xb = x + (size_t)b * 65536;

    // ---- per-thread event geometry: 288 (px,ij) items, <=2 per thread ----
    int xoff[2], sbb[2], silb[2];
    unsigned prevPack[2] = {0u, 0u};
#pragma unroll
    for (int it = 0; it < 2; ++it) {
        int e  = t + it * 256;
        int ec = e < 288 ? e : 0;            // dummy for inactive slots
        int px = ec / 9;
        int ij = ec - px * 9;
        int di = ij / 3;
        int dj = ij - di * 3;
        int row = p + di - 1;
        int col = px + dj - 1;
        bool ok  = ((unsigned)row < 32u) && ((unsigned)col < 32u);
        xoff[it] = ok ? ((row * 32 + col) * 64) : -1;   // sign = halo flag
        sbb[it]  = px * 648 + ij * 16;
        silb[it] = px * 648 + 576 + ij;
    }

    v4f z4 = (v4f){0.f, 0.f, 0.f, 0.f};

    // prologue prefetch for first chunk
    v4f vbuf[2];
#pragma unroll
    for (int it = 0; it < 2; ++it)
        vbuf[it] = (xoff[it] >= 0) ? *(const v4f*)(xb + xoff[it] + ch0 * 4) : z4;

    // one-time zero of the whole basis region
    for (int i4 = t; i4 < 2592; i4 += 256) ((v4f*)sb)[i4] = z4;

    v4f acc[2][4];
#pragma unroll
    for (int i = 0; i < 2; ++i)
#pragma unroll
        for (int n = 0; n < 4; ++n) acc[i][n] = z4;

    __syncthreads();   // basis zeroed, prologue loads drained here (one-time)

    for (int gch = ch0; gch < ch1; ++gch) {
        // ---- scatter: 4 channels per item from one prefetched v4f ----
#pragma unroll
        for (int it = 0; it < 2; ++it) {
            if (t + it * 256 < 288) {
                v4f xv = vbuf[it];
                unsigned pp = prevPack[it];
                unsigned np = 0;
                _Float16* rp = sb + sbb[it];
                _Float16* sp = sb + silb[it];
#pragma unroll
                for (int cl = 0; cl < 4; ++cl) {
                    float v  = xv[cl];
                    float xc = fminf(fmaxf(v, -1.f), 1.f);
                    float tt = (xc + 1.f) * 7.5f;
                    int idx  = (int)tt;
                    if (idx > 14) idx = 14;
                    float fr = tt - (float)idx;
                    float sv = v * __builtin_amdgcn_rcpf(1.f + __expf(-v));
                    _Float16* q = rp + cl * 144;
                    if (gch > ch0) {             // self-clear previous entries
                        int pi = (pp >> (cl * 8)) & 255;
                        q[pi]     = (_Float16)0.f;
                        q[pi + 1] = (_Float16)0.f;
                    }
                    q[idx]     = (_Float16)(1.f - fr);
                    q[idx + 1] = (_Float16)fr;
                    sp[cl * 16] = (_Float16)sv;
                    np |= (unsigned)idx << (cl * 8);
                }
                prevPack[it] = np;
            }
        }
        __syncthreads();
        // ---- prefetch next chunk's x AFTER the barrier: the compiler's
        // vmcnt(0) drain then lands at the NEXT barrier, under the MFMA phase
        if (gch + 1 < ch1) {
#pragma unroll
            for (int it = 0; it < 2; ++it)
                vbuf[it] = (xoff[it] >= 0)
                         ? *(const v4f*)(xb + xoff[it] + (gch + 1) * 4) : z4;
        }
        // ---- MFMA: 20 ksteps, this wave takes 5; 2-deep pipelined ----
        const _Float16* ap = sb + m * 648 + (wv * 5) * 32 + kq * 8;
        const v8h* bp = (const v8h*)wsw + ((size_t)gch * 20 + wv * 5) * 256 + lane;
        v8h a0c = *(const v8h*)ap;
        v8h a1c = *(const v8h*)(ap + 16 * 648);
        v8h b0c = bp[0], b1c = bp[64], b2c = bp[128], b3c = bp[192];
#pragma unroll
        for (int s = 0; s < 5; ++s) {
            v8h a0n, a1n, b0n, b1n, b2n, b3n;
            if (s < 4) {
                const _Float16* ap2 = ap + (s + 1) * 32;
                a0n = *(const v8h*)ap2;
                a1n = *(const v8h*)(ap2 + 16 * 648);
                const v8h* bp2 = bp + (s + 1) * 256;
                b0n = bp2[0];
                b1n = bp2[64];
                b2n = bp2[128];
                b3n = bp2[192];
            }
            acc[0][0] = __builtin_amdgcn_mfma_f32_16x16x32_f16(a0c, b0c, acc[0][0], 0, 0, 0);
            acc[0][1] = __builtin_amdgcn_mfma_f32_16x16x32_f16(a0c, b1c, acc[0][1], 0, 0, 0);
            acc[0][2] = __builtin_amdgcn_mfma_f32_16x16x32_f16(a0c, b2c, acc[0][2], 0, 0, 0);
            acc[0][3] = __builtin_amdgcn_mfma_f32_16x16x32_f16(a0c, b3c, acc[0][3], 0, 0, 0);
            acc[1][0] = __builtin_amdgcn_mfma_f32_16x16x32_f16(a1c, b0c, acc[1][0], 0, 0, 0);
            acc[1][1] = __builtin_amdgcn_mfma_f32_16x16x32_f16(a1c, b1c, acc[1][1], 0, 0, 0);
            acc[1][2] = __builtin_amdgcn_mfma_f32_16x16x32_f16(a1c, b2c, acc[1][2], 0, 0, 0);
            acc[1][3] = __builtin_amdgcn_mfma_f32_16x16x32_f16(a1c, b3c, acc[1][3], 0, 0, 0);
            if (s < 4) {
                a0c = a0n; a1c = a1n;
                b0c = b0n; b1c = b1n; b2c = b2n; b3c = b3n;
            }
        }
        __syncthreads();
    }

    // ---- 4-wave LDS reduction, then coalesced atomicAdd into out ----
#pragma unroll
    for (int mt = 0; mt < 2; ++mt)
#pragma unroll
        for (int nt = 0; nt < 4; ++nt)
#pragma unroll
            for (int r = 0; r < 4; ++r)
                red[wv * 2080 + (mt * 16 + kq * 4 + r) * 65 + nt * 16 + m] = acc[mt][nt][r];
    __syncthreads();
    int f = t & 63, pxg = t >> 6;
    float* op = out + (size_t)rowid * 2048 + f;
#pragma unroll
    for (int i = 0; i < 8; ++i) {
        int px = pxg * 8 + i;
        float s = red[px * 65 + f] + red[2080 + px * 65 + f]
                + red[4160 + px * 65 + f] + red[6240 + px * 65 + f];
        atomicAdd(op + px * 64, s);
    }
}

extern "C" void kernel_launch(void* const* d_in, const int* in_sizes, int n_in,
                              void* d_out, int out_size, void* d_ws, size_t ws_size,
                              hipStream_t stream) {
    const float* x  = (const float*)d_in[0];
    const float* cp = (const float*)d_in[1];
    const float* w1 = (const float*)d_in[2];
    const float* w2 = (const float*)d_in[3];
    _Float16* wsw = (_Float16*)d_ws;                       // 1.31 MB
    float*    outp = (float*)d_out;

    prep_wsw<<<512, 256, 0, stream>>>(cp, w1, w2, wsw, outp);
    kan_mfma<<<768, 256, 0, stream>>>(x, wsw, outp);
}